// Round 4
// baseline (2447.920 us; speedup 1.0000x reference)
//
#include <hip/hip_runtime.h>
#include <math.h>

#define FIN 500
#define NHID 64
#define NCLS 40
#define NLAYERS 8
#define PTILE 16384              // edges per partition block
#define RSHIFT 12                // 4096 rows per fine bucket
#define RROWS 4096
#define NCHUNK 4                 // col chunks of 25000 (3.2 MB of h < 4 MB L2/XCD)
#define CDIV 25000u

typedef _Float16 half8 __attribute__((ext_vector_type(8)));
typedef float f32x4 __attribute__((ext_vector_type(4)));

__device__ __forceinline__ int col_chunk(int c) {
  int ch = (int)((unsigned)c / CDIV);
  return (ch > NCHUNK - 1) ? (NCHUNK - 1) : ch;
}

// ---------------- prep: transpose weights to fp16 [c][k] ----------------
__global__ __launch_bounds__(256) void k_prep(
    const float* __restrict__ Wi, const float* __restrict__ Wc,
    _Float16* __restrict__ WtIn, _Float16* __restrict__ WcT) {
  const int t = blockIdx.x * 256 + threadIdx.x;
  const int stride = gridDim.x * 256;
  for (int i = t; i < 64 * 512; i += stride) {
    int c = i >> 9, k = i & 511;
    WtIn[i] = (k < FIN) ? (_Float16)Wi[k * 64 + c] : (_Float16)0.f;
  }
  for (int i = t; i < NLAYERS * 64 * 64; i += stride) {
    int l = i >> 12, rem = i & 4095, c = rem >> 6, k = rem & 63;
    WcT[i] = (_Float16)Wc[l * 4096 + k * 64 + c];
  }
}

__device__ __forceinline__ half8 load_a_frag(const float* __restrict__ xrow, int gk) {
  half8 a;
  if (gk + 7 < FIN) {
    float4 u = *reinterpret_cast<const float4*>(xrow + gk);
    float4 v = *reinterpret_cast<const float4*>(xrow + gk + 4);
    a[0] = (_Float16)u.x; a[1] = (_Float16)u.y;
    a[2] = (_Float16)u.z; a[3] = (_Float16)u.w;
    a[4] = (_Float16)v.x; a[5] = (_Float16)v.y;
    a[6] = (_Float16)v.z; a[7] = (_Float16)v.w;
  } else {
#pragma unroll
    for (int j = 0; j < 8; ++j)
      a[j] = (gk + j < FIN) ? (_Float16)xrow[gk + j] : (_Float16)0.f;
  }
  return a;
}

// ---------------- h0 = relu(x @ W_in + b_in) -> fp16, MFMA ----------------
__global__ __launch_bounds__(256) void k_gemm_in(
    const float* __restrict__ x, const _Float16* __restrict__ Wt,
    const float* __restrict__ b, _Float16* __restrict__ h0, int n) {
  const int lane = threadIdx.x & 63;
  const int wv = threadIdx.x >> 6;
  const int row0 = blockIdx.x * 64 + wv * 16;
  const int arow = row0 + (lane & 15);
  const int gr = (arow < n) ? arow : (n - 1);
  const int kg = (lane >> 4) * 8;
  const float* xrow = x + (size_t)gr * FIN;
  f32x4 acc[4];
#pragma unroll
  for (int ct = 0; ct < 4; ++ct) acc[ct] = (f32x4){0.f, 0.f, 0.f, 0.f};
  half8 a = load_a_frag(xrow, kg);
#pragma unroll 2
  for (int k0 = 0; k0 < 512; k0 += 32) {
    half8 an = a;
    if (k0 + 32 < 512) an = load_a_frag(xrow, k0 + 32 + kg);
#pragma unroll
    for (int ct = 0; ct < 4; ++ct) {
      const half8 bf = *reinterpret_cast<const half8*>(
          Wt + (size_t)(ct * 16 + (lane & 15)) * 512 + k0 + kg);
      acc[ct] = __builtin_amdgcn_mfma_f32_16x16x32_f16(a, bf, acc[ct], 0, 0, 0);
    }
    a = an;
  }
  const int orow = row0 + (lane >> 4) * 4;
#pragma unroll
  for (int ct = 0; ct < 4; ++ct) {
    const int c = ct * 16 + (lane & 15);
    const float bb = b[c];
#pragma unroll
    for (int i = 0; i < 4; ++i) {
      const int rr = orow + i;
      if (rr < n)
        h0[(size_t)rr * NHID + c] = (_Float16)fmaxf(acc[ct][i] + bb, 0.f);
    }
  }
}

// ---------------- coarse histogram: (chunk, row>>12) buckets ----------------
__global__ __launch_bounds__(256) void k_chist(
    const int* __restrict__ row, const int* __restrict__ col,
    int* __restrict__ ccnt, int e_total, int rh) {
  __shared__ int hist[256];
  const int tid = threadIdx.x;
  hist[tid] = 0;
  __syncthreads();
  const int e0 = blockIdx.x * PTILE;
  for (int t = 0; t < PTILE / 256; ++t) {
    int e = e0 + t * 256 + tid;
    if (e < e_total)
      atomicAdd(&hist[col_chunk(col[e]) * rh + (row[e] >> RSHIFT)], 1);
  }
  __syncthreads();
  if (hist[tid]) atomicAdd(&ccnt[tid], hist[tid]);
}

// ---------------- scan coarse counts -> cbase, bcur ----------------
__global__ __launch_bounds__(256) void k_cscan(
    const int* __restrict__ ccnt, int* __restrict__ cbase,
    int* __restrict__ bcur, int nbC) {
  __shared__ int sh[257];
  const int t = threadIdx.x;
  sh[t] = (t < nbC) ? ccnt[t] : 0;
  __syncthreads();
  if (t == 0) {
    int run = 0;
    for (int i = 0; i < 256; ++i) { int v = sh[i]; sh[i] = run; run += v; }
    sh[256] = run;
  }
  __syncthreads();
  if (t <= nbC) cbase[t] = sh[t];
  if (t < nbC) bcur[t] = sh[t];
}

// ---------------- pass 1: block-local coarse partition ----------------
__global__ __launch_bounds__(256) void k_part2(
    const int* __restrict__ row, const int* __restrict__ col,
    const float* __restrict__ w, int* __restrict__ bcurG,
    int2* __restrict__ staged, int e_total, int nbC, int rh) {
  __shared__ int hist[256];
  __shared__ int cur[256];
  const int tid = threadIdx.x;
  const int e0 = blockIdx.x * PTILE;
  if (tid < nbC) hist[tid] = 0;
  __syncthreads();
  for (int t = 0; t < PTILE / 256; ++t) {
    int e = e0 + t * 256 + tid;
    if (e < e_total)
      atomicAdd(&hist[col_chunk(col[e]) * rh + (row[e] >> RSHIFT)], 1);
  }
  __syncthreads();
  if (tid < nbC) {
    int h = hist[tid];
    cur[tid] = h ? atomicAdd(&bcurG[tid], h) : 0;
  }
  __syncthreads();
  for (int t = 0; t < PTILE / 256; ++t) {
    int e = e0 + t * 256 + tid;
    if (e < e_total) {
      int r = row[e], c = col[e];
      int pos = atomicAdd(&cur[col_chunk(c) * rh + (r >> RSHIFT)], 1);
      staged[pos] = make_int2(((r & (RROWS - 1)) << 17) | c, __float_as_int(w[e]));
    }
  }
}

// ------- pass 2: per-bucket 4096-row hist + scan -> ptr2; place edges -------
// sorted keeps the local-row bits (used by k_fused for the S-tile row).
__global__ __launch_bounds__(256) void k_rebin4(
    const int* __restrict__ cbase, const int2* __restrict__ staged,
    int2* __restrict__ sorted, int* __restrict__ ptr2, int rh) {
  __shared__ int rcnt[RROWS];
  __shared__ int cur[RROWS];
  __shared__ int wsum[4];
  const int tid = threadIdx.x;
  const int k = blockIdx.x / rh;
  const int rhigh = blockIdx.x - k * rh;
  const int bstart = cbase[blockIdx.x], bend = cbase[blockIdx.x + 1];
  for (int i = tid; i < RROWS; i += 256) rcnt[i] = 0;
  __syncthreads();
  for (int i = bstart + tid; i < bend; i += 256)
    atomicAdd(&rcnt[staged[i].x >> 17], 1);
  __syncthreads();
  const int base = tid * 16;
  int s = 0;
#pragma unroll
  for (int j = 0; j < 16; ++j) s += rcnt[base + j];
  const int lane = tid & 63, wid = tid >> 6;
  int incl = s;
#pragma unroll
  for (int off = 1; off < 64; off <<= 1) {
    int u = __shfl_up(incl, off, 64);
    if (lane >= off) incl += u;
  }
  if (lane == 63) wsum[wid] = incl;
  __syncthreads();
  int woff = 0;
  for (int i = 0; i < wid; ++i) woff += wsum[i];
  int run = bstart + (incl - s) + woff;
  int* p2 = ptr2 + (size_t)k * (rh << RSHIFT) + (rhigh << RSHIFT);
#pragma unroll
  for (int j = 0; j < 16; ++j) {
    int c = rcnt[base + j];
    p2[base + j] = run;
    cur[base + j] = run;
    run += c;
  }
  __syncthreads();
  for (int i = bstart + tid; i < bend; i += 256) {
    int2 e = staged[i];
    int pos = atomicAdd(&cur[e.x >> 17], 1);
    sorted[pos] = e;                     // keep local-row bits
  }
}

// ---- fused layer v2: chunk-phased SpMM (8-slot half8 gathers, S in LDS fp32)
//      + blend + MFMA + relu.  Wave owns 16 S-rows exclusively.
__global__ __launch_bounds__(256) void k_fused(
    const int* __restrict__ ptr2, const int2* __restrict__ sorted,
    const _Float16* __restrict__ hin, const _Float16* __restrict__ h0,
    const _Float16* __restrict__ Wt, _Float16* __restrict__ hout,
    float beta, int n, int s2) {
  __shared__ float S[64 * 66];      // stride 66: <=2-way LDS banks (free)
  const int tid = threadIdx.x;
  const int lane = tid & 63;
  const int wid = tid >> 6;
  const int row0 = blockIdx.x * 64;
  const int rbase = row0 + wid * 16;
  // each wave zeros its own 16 rows
  for (int i = lane; i < 16 * 66; i += 64) S[wid * 16 * 66 + i] = 0.f;
  __syncthreads();
  const int fl = lane & 7;          // feature group -> feats fl*8..fl*8+7
  const int sl = lane >> 3;         // slot 0..7 (balanced edge sub-ranges)
  const _Float16* hf = hin + fl * 8;
  for (int k = 0; k < NCHUNK; ++k) {
    const int* p2 = ptr2 + (size_t)k * s2;
    const int A = p2[rbase];
    const int len = p2[rbase + 16] - A;
    int e = A + ((len * sl) >> 3);
    const int mye = A + ((len * (sl + 1)) >> 3);
    int currow = -1;
    float acc[8] = {};
    if (e < mye) {
      int2 d0 = sorted[e];
      half8 v0 = *reinterpret_cast<const half8*>(hf + (size_t)(d0.x & 0x1FFFF) * NHID);
      while (true) {
        const int en = e + 1;
        const bool more = en < mye;
        int2 d1; half8 v1;
        if (more) {                         // next desc+gather in flight
          d1 = sorted[en];
          v1 = *reinterpret_cast<const half8*>(hf + (size_t)(d1.x & 0x1FFFF) * NHID);
        }
        const int tr = (d0.x >> 17) & 63;   // row within 64-row block
        if (tr != currow) {
          if (currow >= 0) {
#pragma unroll
            for (int j = 0; j < 8; ++j)
              atomicAdd(&S[currow * 66 + fl * 8 + j], acc[j]);
          }
          currow = tr;
#pragma unroll
          for (int j = 0; j < 8; ++j) acc[j] = 0.f;
        }
        const float w = __int_as_float(d0.y);
#pragma unroll
        for (int j = 0; j < 8; ++j) acc[j] += w * (float)v0[j];
        if (!more) break;
        e = en; d0 = d1; v0 = v1;
      }
      if (currow >= 0) {
#pragma unroll
        for (int j = 0; j < 8; ++j)
          atomicAdd(&S[currow * 66 + fl * 8 + j], acc[j]);
      }
    }
  }
  __syncthreads();                           // drain ds_adds before reads
  // blend: S = 0.9*S + 0.1*h0 (own rows)
  for (int rr = 0; rr < 16; ++rr) {
    const int r = rbase + rr;
    if (r >= n) break;
    float* sp = &S[(wid * 16 + rr) * 66 + lane];
    *sp = 0.9f * *sp + 0.1f * (float)h0[(size_t)r * NHID + lane];
  }
  __syncthreads();
  // MFMA: wave wid -> rows [wid*16, +16) x 64 cols; a-frags from LDS.
  const int al = lane & 15;
  const int kg = (lane >> 4) * 8;
  const float* sa = &S[(wid * 16 + al) * 66 + kg];
  half8 a0, a1;
#pragma unroll
  for (int j = 0; j < 8; ++j) a0[j] = (_Float16)sa[j];
#pragma unroll
  for (int j = 0; j < 8; ++j) a1[j] = (_Float16)sa[32 + j];
  f32x4 acc[4];
#pragma unroll
  for (int ct = 0; ct < 4; ++ct) acc[ct] = (f32x4){0.f, 0.f, 0.f, 0.f};
#pragma unroll
  for (int ct = 0; ct < 4; ++ct) {
    const int c = ct * 16 + al;
    const half8 b0 = *reinterpret_cast<const half8*>(Wt + c * NHID + kg);
    const half8 b1 = *reinterpret_cast<const half8*>(Wt + c * NHID + 32 + kg);
    acc[ct] = __builtin_amdgcn_mfma_f32_16x16x32_f16(a0, b0, acc[ct], 0, 0, 0);
    acc[ct] = __builtin_amdgcn_mfma_f32_16x16x32_f16(a1, b1, acc[ct], 0, 0, 0);
  }
  const float g = 1.f - beta;
  const int ri = (lane >> 4) * 4;
#pragma unroll
  for (int ct = 0; ct < 4; ++ct) {
    const int c = ct * 16 + al;
#pragma unroll
    for (int i = 0; i < 4; ++i) {
      const int r = rbase + ri + i;
      if (r < n) {
        const float sv = S[(wid * 16 + ri + i) * 66 + c];
        hout[(size_t)r * NHID + c] =
            (_Float16)fmaxf(beta * acc[ct][i] + g * sv, 0.f);
      }
    }
  }
}

// ---------------- out = log_softmax(h @ W_out + b_out), persistent ----------------
__global__ __launch_bounds__(256) void k_out(
    const _Float16* __restrict__ h, const float* __restrict__ Wo,
    const float* __restrict__ bo, float* __restrict__ out, int n, int wstride) {
  const int lane = threadIdx.x & 63;
  const int j = (lane < NCLS) ? lane : (NCLS - 1);
  for (int r = blockIdx.x * 4 + (threadIdx.x >> 6); r < n; r += wstride) {
    const float hv = (float)h[(size_t)r * NHID + lane];
    float acc = bo[j];
#pragma unroll 16
    for (int k = 0; k < NHID; ++k) {
      float hk = __shfl(hv, k, 64);
      acc += hk * Wo[k * NCLS + j];
    }
    float v = (lane < NCLS) ? acc : -INFINITY;
    float m = v;
#pragma unroll
    for (int off = 32; off; off >>= 1) m = fmaxf(m, __shfl_xor(m, off, 64));
    float e = (lane < NCLS) ? expf(acc - m) : 0.f;
    float s = e;
#pragma unroll
    for (int off = 32; off; off >>= 1) s += __shfl_xor(s, off, 64);
    if (lane < NCLS) out[(size_t)r * NCLS + lane] = acc - m - logf(s);
  }
}

extern "C" void kernel_launch(void* const* d_in, const int* in_sizes, int n_in,
                              void* d_out, int out_size, void* d_ws, size_t ws_size,
                              hipStream_t stream) {
  const float* x  = (const float*)d_in[0];
  const int* row  = (const int*)d_in[1];
  const int* col  = (const int*)d_in[2];
  const float* ew = (const float*)d_in[3];
  const float* Wi = (const float*)d_in[4];
  const float* bi = (const float*)d_in[5];
  const float* Wc = (const float*)d_in[6];
  const float* Wo = (const float*)d_in[7];
  const float* bo = (const float*)d_in[8];
  float* out = (float*)d_out;

  const int n = in_sizes[0] / FIN;   // 100000
  const int E = in_sizes[1];         // 3200000

  const int rh = (n + RROWS - 1) >> RSHIFT;       // 25
  const int s2 = rh << RSHIFT;                    // 102400 (ptr2 stride per chunk)
  const int nbC2 = NCHUNK * rh;                   // 100

  // workspace layout (~90 MB)
  _Float16* h0h = (_Float16*)d_ws;                      // n*64 f16
  _Float16* hhA = h0h + (size_t)n * NHID;               // n*64 f16
  _Float16* hhB = hhA + (size_t)n * NHID;               // n*64 f16
  int2* staged  = (int2*)(hhB + (size_t)n * NHID);      // E int2
  int2* sorted  = staged + E;                           // E int2
  int*  ptr2    = (int*)(sorted + E);                   // NCHUNK*s2 + 1
  int*  ccnt    = ptr2 + (size_t)NCHUNK * s2 + 1;       // 256
  int*  cbase   = ccnt + 256;                           // 257
  int*  bcur    = cbase + 257;                          // 256
  _Float16* WtIn = (_Float16*)(((uintptr_t)(bcur + 256) + 63) & ~(uintptr_t)63);
  _Float16* WcT  = WtIn + 64 * 512;                     // 8*64*64 f16

  const int nPB = (E + PTILE - 1) / PTILE;              // 196
  const int nBF = (n + 63) / 64;                        // 1563
  dim3 blk(256);

  // ---- CSR build keyed by (col-chunk, row) ----
  hipMemsetAsync(ccnt, 0, 256 * sizeof(int), stream);
  k_chist<<<dim3(nPB), blk, 0, stream>>>(row, col, ccnt, E, rh);
  k_cscan<<<dim3(1), blk, 0, stream>>>(ccnt, cbase, bcur, nbC2);
  k_part2<<<dim3(nPB), blk, 0, stream>>>(row, col, ew, bcur, staged, E, nbC2, rh);
  k_rebin4<<<dim3(nbC2), blk, 0, stream>>>(cbase, staged, sorted, ptr2, rh);

  // ---- fp16 weight transposes ----
  k_prep<<<dim3(64), blk, 0, stream>>>(Wi, Wc, WtIn, WcT);

  // ---- dense input projection (MFMA) ----
  k_gemm_in<<<dim3(nBF), blk, 0, stream>>>(x, WtIn, bi, h0h, n);

  // ---- 8 GCNII layers: fused chunk-phased SpMM + blend + GEMM + relu ----
  const _Float16* hin = h0h;
  for (int l = 0; l < NLAYERS; ++l) {
    _Float16* hout = (l & 1) ? hhB : hhA;
    float beta = logf(0.5f / (float)(l + 1) + 1.f);
    k_fused<<<dim3(nBF), blk, 0, stream>>>(
        ptr2, sorted, hin, h0h, WcT + (size_t)l * NHID * NHID, hout, beta, n, s2);
    hin = hout;
  }
  const int outBlocks = 2048;
  k_out<<<dim3(outBlocks), blk, 0, stream>>>(hin, Wo, bo, out, n, outBlocks * 4);
}

// Round 5
// 1161.965 us; speedup vs baseline: 2.1067x; 2.1067x over previous
//
#include <hip/hip_runtime.h>
#include <math.h>

#define FIN 500
#define NHID 64
#define NCLS 40
#define NLAYERS 8
#define PTILE 16384              // edges per partition block
#define RSHIFT 12                // 4096 rows per fine bucket
#define RROWS 4096
#define NCHUNK 6                 // col chunks of 16667 cols = 2.13 MB of h < 4 MB L2/XCD
#define CDIV 16667u

typedef _Float16 half8 __attribute__((ext_vector_type(8)));
typedef float f32x4 __attribute__((ext_vector_type(4)));

__device__ __forceinline__ int col_chunk(int c) {
  int ch = (int)((unsigned)c / CDIV);
  return (ch > NCHUNK - 1) ? (NCHUNK - 1) : ch;
}

// ---------------- prep: transpose weights to fp16 [c][k] ----------------
__global__ __launch_bounds__(256) void k_prep(
    const float* __restrict__ Wi, const float* __restrict__ Wc,
    _Float16* __restrict__ WtIn, _Float16* __restrict__ WcT) {
  const int t = blockIdx.x * 256 + threadIdx.x;
  const int stride = gridDim.x * 256;
  for (int i = t; i < 64 * 512; i += stride) {
    int c = i >> 9, k = i & 511;
    WtIn[i] = (k < FIN) ? (_Float16)Wi[k * 64 + c] : (_Float16)0.f;
  }
  for (int i = t; i < NLAYERS * 64 * 64; i += stride) {
    int l = i >> 12, rem = i & 4095, c = rem >> 6, k = rem & 63;
    WcT[i] = (_Float16)Wc[l * 4096 + k * 64 + c];
  }
}

__device__ __forceinline__ half8 load_a_frag(const float* __restrict__ xrow, int gk) {
  half8 a;
  if (gk + 7 < FIN) {
    float4 u = *reinterpret_cast<const float4*>(xrow + gk);
    float4 v = *reinterpret_cast<const float4*>(xrow + gk + 4);
    a[0] = (_Float16)u.x; a[1] = (_Float16)u.y;
    a[2] = (_Float16)u.z; a[3] = (_Float16)u.w;
    a[4] = (_Float16)v.x; a[5] = (_Float16)v.y;
    a[6] = (_Float16)v.z; a[7] = (_Float16)v.w;
  } else {
#pragma unroll
    for (int j = 0; j < 8; ++j)
      a[j] = (gk + j < FIN) ? (_Float16)xrow[gk + j] : (_Float16)0.f;
  }
  return a;
}

// ---------------- h0 = relu(x @ W_in + b_in) -> fp16, MFMA ----------------
__global__ __launch_bounds__(256) void k_gemm_in(
    const float* __restrict__ x, const _Float16* __restrict__ Wt,
    const float* __restrict__ b, _Float16* __restrict__ h0, int n) {
  const int lane = threadIdx.x & 63;
  const int wv = threadIdx.x >> 6;
  const int row0 = blockIdx.x * 64 + wv * 16;
  const int arow = row0 + (lane & 15);
  const int gr = (arow < n) ? arow : (n - 1);
  const int kg = (lane >> 4) * 8;
  const float* xrow = x + (size_t)gr * FIN;
  f32x4 acc[4];
#pragma unroll
  for (int ct = 0; ct < 4; ++ct) acc[ct] = (f32x4){0.f, 0.f, 0.f, 0.f};
  half8 a = load_a_frag(xrow, kg);
#pragma unroll 2
  for (int k0 = 0; k0 < 512; k0 += 32) {
    half8 an = a;
    if (k0 + 32 < 512) an = load_a_frag(xrow, k0 + 32 + kg);
#pragma unroll
    for (int ct = 0; ct < 4; ++ct) {
      const half8 bf = *reinterpret_cast<const half8*>(
          Wt + (size_t)(ct * 16 + (lane & 15)) * 512 + k0 + kg);
      acc[ct] = __builtin_amdgcn_mfma_f32_16x16x32_f16(a, bf, acc[ct], 0, 0, 0);
    }
    a = an;
  }
  const int orow = row0 + (lane >> 4) * 4;
#pragma unroll
  for (int ct = 0; ct < 4; ++ct) {
    const int c = ct * 16 + (lane & 15);
    const float bb = b[c];
#pragma unroll
    for (int i = 0; i < 4; ++i) {
      const int rr = orow + i;
      if (rr < n)
        h0[(size_t)rr * NHID + c] = (_Float16)fmaxf(acc[ct][i] + bb, 0.f);
    }
  }
}

// ---------------- coarse histogram: (chunk, row>>12) buckets ----------------
__global__ __launch_bounds__(256) void k_chist(
    const int* __restrict__ row, const int* __restrict__ col,
    int* __restrict__ ccnt, int e_total, int rh) {
  __shared__ int hist[256];
  const int tid = threadIdx.x;
  hist[tid] = 0;
  __syncthreads();
  const int e0 = blockIdx.x * PTILE;
  for (int t = 0; t < PTILE / 256; ++t) {
    int e = e0 + t * 256 + tid;
    if (e < e_total)
      atomicAdd(&hist[col_chunk(col[e]) * rh + (row[e] >> RSHIFT)], 1);
  }
  __syncthreads();
  if (hist[tid]) atomicAdd(&ccnt[tid], hist[tid]);
}

// ---------------- scan coarse counts -> cbase, bcur ----------------
__global__ __launch_bounds__(256) void k_cscan(
    const int* __restrict__ ccnt, int* __restrict__ cbase,
    int* __restrict__ bcur, int nbC) {
  __shared__ int sh[257];
  const int t = threadIdx.x;
  sh[t] = (t < nbC) ? ccnt[t] : 0;
  __syncthreads();
  if (t == 0) {
    int run = 0;
    for (int i = 0; i < 256; ++i) { int v = sh[i]; sh[i] = run; run += v; }
    sh[256] = run;
  }
  __syncthreads();
  if (t <= nbC) cbase[t] = sh[t];
  if (t < nbC) bcur[t] = sh[t];
}

// ---------------- pass 1: block-local coarse partition ----------------
__global__ __launch_bounds__(256) void k_part2(
    const int* __restrict__ row, const int* __restrict__ col,
    const float* __restrict__ w, int* __restrict__ bcurG,
    int2* __restrict__ staged, int e_total, int nbC, int rh) {
  __shared__ int hist[256];
  __shared__ int cur[256];
  const int tid = threadIdx.x;
  const int e0 = blockIdx.x * PTILE;
  if (tid < nbC) hist[tid] = 0;
  __syncthreads();
  for (int t = 0; t < PTILE / 256; ++t) {
    int e = e0 + t * 256 + tid;
    if (e < e_total)
      atomicAdd(&hist[col_chunk(col[e]) * rh + (row[e] >> RSHIFT)], 1);
  }
  __syncthreads();
  if (tid < nbC) {
    int h = hist[tid];
    cur[tid] = h ? atomicAdd(&bcurG[tid], h) : 0;
  }
  __syncthreads();
  for (int t = 0; t < PTILE / 256; ++t) {
    int e = e0 + t * 256 + tid;
    if (e < e_total) {
      int r = row[e], c = col[e];
      int pos = atomicAdd(&cur[col_chunk(c) * rh + (r >> RSHIFT)], 1);
      staged[pos] = make_int2(((r & (RROWS - 1)) << 17) | c, __float_as_int(w[e]));
    }
  }
}

// ------- pass 2: per-bucket 4096-row hist + scan -> ptr2; place edges -------
__global__ __launch_bounds__(256) void k_rebin4(
    const int* __restrict__ cbase, const int2* __restrict__ staged,
    int2* __restrict__ sorted, int* __restrict__ ptr2, int rh) {
  __shared__ int rcnt[RROWS];
  __shared__ int cur[RROWS];
  __shared__ int wsum[4];
  const int tid = threadIdx.x;
  const int k = blockIdx.x / rh;
  const int rhigh = blockIdx.x - k * rh;
  const int bstart = cbase[blockIdx.x], bend = cbase[blockIdx.x + 1];
  for (int i = tid; i < RROWS; i += 256) rcnt[i] = 0;
  __syncthreads();
  for (int i = bstart + tid; i < bend; i += 256)
    atomicAdd(&rcnt[staged[i].x >> 17], 1);
  __syncthreads();
  const int base = tid * 16;
  int s = 0;
#pragma unroll
  for (int j = 0; j < 16; ++j) s += rcnt[base + j];
  const int lane = tid & 63, wid = tid >> 6;
  int incl = s;
#pragma unroll
  for (int off = 1; off < 64; off <<= 1) {
    int u = __shfl_up(incl, off, 64);
    if (lane >= off) incl += u;
  }
  if (lane == 63) wsum[wid] = incl;
  __syncthreads();
  int woff = 0;
  for (int i = 0; i < wid; ++i) woff += wsum[i];
  int run = bstart + (incl - s) + woff;
  int* p2 = ptr2 + (size_t)k * (rh << RSHIFT) + (rhigh << RSHIFT);
#pragma unroll
  for (int j = 0; j < 16; ++j) {
    int c = rcnt[base + j];
    p2[base + j] = run;
    cur[base + j] = run;
    run += c;
  }
  __syncthreads();
  for (int i = bstart + tid; i < bend; i += 256) {
    int2 e = staged[i];
    int pos = atomicAdd(&cur[e.x >> 17], 1);
    sorted[pos] = e;
  }
}

// ---- fused layer v3: chunk-phased SpMM, slot-per-row, reg accumulation ----
// wave = 8 slots x 8 feat-lanes; slot owns rows rbase+sl and rbase+8+sl.
// acc lives in registers across all chunks; S->LDS once; NO barriers, NO atomics.
__global__ __launch_bounds__(256, 8) void k_fused(
    const int* __restrict__ ptr2, const int2* __restrict__ sorted,
    const _Float16* __restrict__ hin, const _Float16* __restrict__ h0,
    const _Float16* __restrict__ Wt, _Float16* __restrict__ hout,
    float beta, int n, int s2) {
  __shared__ float S[64 * 66];      // stride 66: <=2-way LDS banks (free)
  const int tid = threadIdx.x;
  const int lane = tid & 63;
  const int wid = tid >> 6;
  const int rbase = blockIdx.x * 64 + wid * 16;
  const int fl = lane & 7;          // feature group -> feats fl*8..fl*8+7
  const int sl = lane >> 3;         // slot -> row offset
  const _Float16* hf = hin + fl * 8;
  float acc0[8] = {}, acc1[8] = {};
  for (int k = 0; k < NCHUNK; ++k) {
    const int* p2 = ptr2 + (size_t)k * s2;
#pragma unroll
    for (int b = 0; b < 2; ++b) {
      float* acc = b ? acc1 : acc0;
      const int r = rbase + b * 8 + sl;
      int e = p2[r];
      const int e1 = p2[r + 1];
      if (e < e1) {
        int2 d = sorted[e];
        half8 v = *reinterpret_cast<const half8*>(hf + (size_t)(d.x & 0x1FFFF) * NHID);
        for (++e; e < e1; ++e) {
          const int2 dn = sorted[e];                 // next desc+gather in flight
          const half8 vn = *reinterpret_cast<const half8*>(
              hf + (size_t)(dn.x & 0x1FFFF) * NHID);
          const float w = __int_as_float(d.y);
#pragma unroll
          for (int j = 0; j < 8; ++j) acc[j] += w * (float)v[j];
          d = dn; v = vn;
        }
        const float w = __int_as_float(d.y);
#pragma unroll
        for (int j = 0; j < 8; ++j) acc[j] += w * (float)v[j];
      }
    }
  }
  // spill acc -> S (each (row,featgroup) owned by exactly one lane; 2-way banks)
#pragma unroll
  for (int j = 0; j < 8; ++j) S[(wid * 16 + sl) * 66 + fl * 8 + j] = acc0[j];
#pragma unroll
  for (int j = 0; j < 8; ++j) S[(wid * 16 + 8 + sl) * 66 + fl * 8 + j] = acc1[j];
  // blend: S = 0.9*S + 0.1*h0 (wave's own rows; intra-wave LDS ordering only)
  for (int rr = 0; rr < 16; ++rr) {
    const int r = rbase + rr;
    if (r >= n) break;
    float* sp = &S[(wid * 16 + rr) * 66 + lane];
    *sp = 0.9f * *sp + 0.1f * (float)h0[(size_t)r * NHID + lane];
  }
  // MFMA: wave wid -> rows [rbase, rbase+16) x 64 cols; a-frags from own S rows.
  const int al = lane & 15;
  const int kg = (lane >> 4) * 8;
  const float* sa = &S[(wid * 16 + al) * 66 + kg];
  half8 a0, a1;
#pragma unroll
  for (int j = 0; j < 8; ++j) a0[j] = (_Float16)sa[j];
#pragma unroll
  for (int j = 0; j < 8; ++j) a1[j] = (_Float16)sa[32 + j];
  f32x4 acc[4];
#pragma unroll
  for (int ct = 0; ct < 4; ++ct) acc[ct] = (f32x4){0.f, 0.f, 0.f, 0.f};
#pragma unroll
  for (int ct = 0; ct < 4; ++ct) {
    const int c = ct * 16 + al;
    const half8 b0 = *reinterpret_cast<const half8*>(Wt + c * NHID + kg);
    const half8 b1 = *reinterpret_cast<const half8*>(Wt + c * NHID + 32 + kg);
    acc[ct] = __builtin_amdgcn_mfma_f32_16x16x32_f16(a0, b0, acc[ct], 0, 0, 0);
    acc[ct] = __builtin_amdgcn_mfma_f32_16x16x32_f16(a1, b1, acc[ct], 0, 0, 0);
  }
  const float g = 1.f - beta;
  const int ri = (lane >> 4) * 4;
#pragma unroll
  for (int ct = 0; ct < 4; ++ct) {
    const int c = ct * 16 + al;
#pragma unroll
    for (int i = 0; i < 4; ++i) {
      const int r = rbase + ri + i;
      if (r < n) {
        const float sv = S[(wid * 16 + ri + i) * 66 + c];
        hout[(size_t)r * NHID + c] =
            (_Float16)fmaxf(beta * acc[ct][i] + g * sv, 0.f);
      }
    }
  }
}

// ---------------- out = log_softmax(h @ W_out + b_out), persistent ----------------
__global__ __launch_bounds__(256) void k_out(
    const _Float16* __restrict__ h, const float* __restrict__ Wo,
    const float* __restrict__ bo, float* __restrict__ out, int n, int wstride) {
  const int lane = threadIdx.x & 63;
  const int j = (lane < NCLS) ? lane : (NCLS - 1);
  for (int r = blockIdx.x * 4 + (threadIdx.x >> 6); r < n; r += wstride) {
    const float hv = (float)h[(size_t)r * NHID + lane];
    float acc = bo[j];
#pragma unroll 16
    for (int k = 0; k < NHID; ++k) {
      float hk = __shfl(hv, k, 64);
      acc += hk * Wo[k * NCLS + j];
    }
    float v = (lane < NCLS) ? acc : -INFINITY;
    float m = v;
#pragma unroll
    for (int off = 32; off; off >>= 1) m = fmaxf(m, __shfl_xor(m, off, 64));
    float e = (lane < NCLS) ? expf(acc - m) : 0.f;
    float s = e;
#pragma unroll
    for (int off = 32; off; off >>= 1) s += __shfl_xor(s, off, 64);
    if (lane < NCLS) out[(size_t)r * NCLS + lane] = acc - m - logf(s);
  }
}

extern "C" void kernel_launch(void* const* d_in, const int* in_sizes, int n_in,
                              void* d_out, int out_size, void* d_ws, size_t ws_size,
                              hipStream_t stream) {
  const float* x  = (const float*)d_in[0];
  const int* row  = (const int*)d_in[1];
  const int* col  = (const int*)d_in[2];
  const float* ew = (const float*)d_in[3];
  const float* Wi = (const float*)d_in[4];
  const float* bi = (const float*)d_in[5];
  const float* Wc = (const float*)d_in[6];
  const float* Wo = (const float*)d_in[7];
  const float* bo = (const float*)d_in[8];
  float* out = (float*)d_out;

  const int n = in_sizes[0] / FIN;   // 100000
  const int E = in_sizes[1];         // 3200000

  const int rh = (n + RROWS - 1) >> RSHIFT;       // 25
  const int s2 = rh << RSHIFT;                    // 102400 (ptr2 stride per chunk)
  const int nbC2 = NCHUNK * rh;                   // 150

  // workspace layout (~95 MB)
  _Float16* h0h = (_Float16*)d_ws;                      // n*64 f16
  _Float16* hhA = h0h + (size_t)n * NHID;               // n*64 f16
  _Float16* hhB = hhA + (size_t)n * NHID;               // n*64 f16
  int2* staged  = (int2*)(hhB + (size_t)n * NHID);      // E int2
  int2* sorted  = staged + E;                           // E int2
  int*  ptr2    = (int*)(sorted + E);                   // NCHUNK*s2 + 1
  int*  ccnt    = ptr2 + (size_t)NCHUNK * s2 + 1;       // 256
  int*  cbase   = ccnt + 256;                           // 257
  int*  bcur    = cbase + 257;                          // 256
  _Float16* WtIn = (_Float16*)(((uintptr_t)(bcur + 256) + 63) & ~(uintptr_t)63);
  _Float16* WcT  = WtIn + 64 * 512;                     // 8*64*64 f16

  const int nPB = (E + PTILE - 1) / PTILE;              // 196
  const int nBF = (n + 63) / 64;                        // 1563
  dim3 blk(256);

  // ---- CSR build keyed by (col-chunk, row) ----
  hipMemsetAsync(ccnt, 0, 256 * sizeof(int), stream);
  k_chist<<<dim3(nPB), blk, 0, stream>>>(row, col, ccnt, E, rh);
  k_cscan<<<dim3(1), blk, 0, stream>>>(ccnt, cbase, bcur, nbC2);
  k_part2<<<dim3(nPB), blk, 0, stream>>>(row, col, ew, bcur, staged, E, nbC2, rh);
  k_rebin4<<<dim3(nbC2), blk, 0, stream>>>(cbase, staged, sorted, ptr2, rh);

  // ---- fp16 weight transposes ----
  k_prep<<<dim3(64), blk, 0, stream>>>(Wi, Wc, WtIn, WcT);

  // ---- dense input projection (MFMA) ----
  k_gemm_in<<<dim3(nBF), blk, 0, stream>>>(x, WtIn, bi, h0h, n);

  // ---- 8 GCNII layers: fused chunk-phased SpMM + blend + GEMM + relu ----
  const _Float16* hin = h0h;
  for (int l = 0; l < NLAYERS; ++l) {
    _Float16* hout = (l & 1) ? hhB : hhA;
    float beta = logf(0.5f / (float)(l + 1) + 1.f);
    k_fused<<<dim3(nBF), blk, 0, stream>>>(
        ptr2, sorted, hin, h0h, WcT + (size_t)l * NHID * NHID, hout, beta, n, s2);
    hin = hout;
  }
  const int outBlocks = 2048;
  k_out<<<dim3(outBlocks), blk, 0, stream>>>(hin, Wo, bo, out, n, outBlocks * 4);
}